// Round 1
// baseline (2269.992 us; speedup 1.0000x reference)
//
#include <hip/hip_runtime.h>
#include <hip/hip_bf16.h>

#define D_IN  128
#define D_HID 256
#define D_OUT 128

__device__ __forceinline__ float gelu_exact(float x) {
    return 0.5f * x * (1.0f + erff(x * 0.70710678118654752f));
}

// Detect edge_index dtype: OR of odd 32-bit words over the first 2E words.
// int64 (values < 50000) -> all high words zero -> flag stays 0.
// int32 -> odd words are random indices -> flag becomes nonzero.
__global__ void detect_kernel(const unsigned int* __restrict__ w,
                              unsigned int* __restrict__ flag, int E) {
    unsigned int v = 0;
    for (long long i = (long long)blockIdx.x * blockDim.x + threadIdx.x; i < E;
         i += (long long)gridDim.x * blockDim.x)
        v |= w[2 * i + 1];
    v |= __shfl_xor(v, 32);
    v |= __shfl_xor(v, 16);
    v |= __shfl_xor(v, 8);
    v |= __shfl_xor(v, 4);
    v |= __shfl_xor(v, 2);
    v |= __shfl_xor(v, 1);
    if ((threadIdx.x & 63) == 0 && v) atomicOr(flag, 1u);
}

// One directed edge per 32-lane group; each lane moves a float4 (128 floats/edge).
__global__ __launch_bounds__(256) void scatter_kernel(
        const float* __restrict__ x, const void* __restrict__ ei,
        const unsigned int* __restrict__ flag, float* __restrict__ agg, int E) {
    int task = blockIdx.x * (blockDim.x >> 5) + (threadIdx.x >> 5);
    int lane = threadIdx.x & 31;
    if (task >= 2 * E) return;
    int e = task >> 1;
    int dir = task & 1;
    long long s, r;
    if (*flag == 0u) {  // int64 indices
        const long long* p = (const long long*)ei;
        s = p[e]; r = p[E + e];
    } else {            // int32 indices
        const int* p = (const int*)ei;
        s = p[e]; r = p[E + e];
    }
    if (dir) { long long t = s; s = r; r = t; }
    float4 v = ((const float4*)(x + s * D_IN))[lane];
    float* dst = agg + r * D_IN + lane * 4;
    atomicAdd(dst + 0, v.x);
    atomicAdd(dst + 1, v.y);
    atomicAdd(dst + 2, v.z);
    atomicAdd(dst + 3, v.w);
}

// C[M,N] = act(A[M,K] @ B[K,N] + bias). BM=BN=64, BK=16, 256 thr, 4x4/thread.
template<bool GELU>
__global__ __launch_bounds__(256) void gemm_kernel(
        const float* __restrict__ A, const float* __restrict__ B,
        const float* __restrict__ bias, float* __restrict__ C,
        int M, int N, int K) {
    __shared__ float As[16][68];
    __shared__ float Bs[16][68];
    int tid = threadIdx.x;
    int tx = tid & 15, ty = tid >> 4;
    int m0 = blockIdx.x * 64, n0 = blockIdx.y * 64;
    float acc[4][4] = {};
    int arow = tid >> 2, akq = (tid & 3) * 4;   // A: 64 rows x 16 k, float4/thread
    int bkk  = tid >> 4, bn  = (tid & 15) * 4;  // B: 16 k x 64 n, float4/thread

    for (int k0 = 0; k0 < K; k0 += 16) {
        float4 a4 = make_float4(0.f, 0.f, 0.f, 0.f);
        if (m0 + arow < M)
            a4 = *(const float4*)(A + (long long)(m0 + arow) * K + k0 + akq);
        *(float4*)(&Bs[bkk][bn]) = *(const float4*)(B + (long long)(k0 + bkk) * N + n0 + bn);
        As[akq + 0][arow] = a4.x;
        As[akq + 1][arow] = a4.y;
        As[akq + 2][arow] = a4.z;
        As[akq + 3][arow] = a4.w;
        __syncthreads();
#pragma unroll
        for (int kk = 0; kk < 16; ++kk) {
            float4 a = *(const float4*)(&As[kk][ty * 4]);
            float4 b = *(const float4*)(&Bs[kk][tx * 4]);
            float av[4] = {a.x, a.y, a.z, a.w};
            float bv[4] = {b.x, b.y, b.z, b.w};
#pragma unroll
            for (int i = 0; i < 4; ++i)
#pragma unroll
                for (int j = 0; j < 4; ++j)
                    acc[i][j] = fmaf(av[i], bv[j], acc[i][j]);
        }
        __syncthreads();
    }
#pragma unroll
    for (int i = 0; i < 4; ++i) {
        int m = m0 + ty * 4 + i;
        if (m < M) {
            float4 o;
            float* op = (float*)&o;
#pragma unroll
            for (int j = 0; j < 4; ++j) {
                float v = acc[i][j] + bias[n0 + tx * 4 + j];
                op[j] = GELU ? gelu_exact(v) : v;
            }
            *(float4*)(C + (long long)m * N + n0 + tx * 4) = o;
        }
    }
}

// out = LayerNorm(A[M,256] @ W3[256,128] + b3) * g + beta.
// BM=32, BN=128(full), BK=8, 256 thr (ty=tid/32 in 0..7, tx=tid%32), 4x4/thread.
// Each row lives in one 32-lane half-wave -> shfl_xor LN reduction.
__global__ __launch_bounds__(256) void gemm_ln_kernel(
        const float* __restrict__ A, const float* __restrict__ B,
        const float* __restrict__ bias, const float* __restrict__ g,
        const float* __restrict__ beta, float* __restrict__ out, int M) {
    __shared__ float As[8][36];
    __shared__ float Bs[8][132];
    int tid = threadIdx.x;
    int tx = tid & 31, ty = tid >> 5;
    int m0 = blockIdx.x * 32;
    float acc[4][4] = {};
    int arow = tid >> 3, akq = tid & 7;  // A: 32 rows x 8 k, 1 float/thread

    for (int k0 = 0; k0 < 256; k0 += 8) {
        float av = 0.f;
        if (m0 + arow < M)
            av = A[(long long)(m0 + arow) * 256 + k0 + akq];
        As[akq][arow] = av;
        *(float4*)(&Bs[ty][tx * 4]) = *(const float4*)(B + (long long)(k0 + ty) * 128 + tx * 4);
        __syncthreads();
#pragma unroll
        for (int kk = 0; kk < 8; ++kk) {
            float4 a = *(const float4*)(&As[kk][ty * 4]);
            float4 b = *(const float4*)(&Bs[kk][tx * 4]);
            float av4[4] = {a.x, a.y, a.z, a.w};
            float bv4[4] = {b.x, b.y, b.z, b.w};
#pragma unroll
            for (int i = 0; i < 4; ++i)
#pragma unroll
                for (int j = 0; j < 4; ++j)
                    acc[i][j] = fmaf(av4[i], bv4[j], acc[i][j]);
        }
        __syncthreads();
    }

    float mu[4], rs[4];
#pragma unroll
    for (int i = 0; i < 4; ++i) {
        float s = 0.f, q = 0.f;
#pragma unroll
        for (int j = 0; j < 4; ++j) {
            float v = acc[i][j] + bias[tx * 4 + j];
            acc[i][j] = v;
            s += v;
            q += v * v;
        }
#pragma unroll
        for (int msk = 16; msk >= 1; msk >>= 1) {
            s += __shfl_xor(s, msk);
            q += __shfl_xor(q, msk);
        }
        float m = s * (1.f / 128.f);
        float var = q * (1.f / 128.f) - m * m;
        mu[i] = m;
        rs[i] = rsqrtf(var + 1e-5f);
    }
#pragma unroll
    for (int i = 0; i < 4; ++i) {
        int m = m0 + ty * 4 + i;
        if (m < M) {
            float4 o;
            float* op = (float*)&o;
#pragma unroll
            for (int j = 0; j < 4; ++j)
                op[j] = (acc[i][j] - mu[i]) * rs[i] * g[tx * 4 + j] + beta[tx * 4 + j];
            *(float4*)(out + (long long)m * 128 + tx * 4) = o;
        }
    }
}

extern "C" void kernel_launch(void* const* d_in, const int* in_sizes, int n_in,
                              void* d_out, int out_size, void* d_ws, size_t ws_size,
                              hipStream_t stream) {
    const float* x    = (const float*)d_in[0];
    const void*  ei   = d_in[1];
    const float* W1   = (const float*)d_in[2];
    const float* b1   = (const float*)d_in[3];
    const float* W2   = (const float*)d_in[4];
    const float* b2   = (const float*)d_in[5];
    const float* W3   = (const float*)d_in[6];
    const float* b3   = (const float*)d_in[7];
    const float* ln_g = (const float*)d_in[8];
    const float* ln_b = (const float*)d_in[9];
    float* out = (float*)d_out;

    int M = in_sizes[0] / D_IN;   // 50000 nodes
    int E = in_sizes[1] / 2;      // 600000 edges

    char* ws = (char*)d_ws;
    unsigned int* flag = (unsigned int*)ws;
    size_t regSize = (size_t)M * D_HID * sizeof(float);  // 51.2 MB
    float* bufA = (float*)(ws + 256);
    float* bufB = (float*)(ws + 256 + regSize);
    float* agg = bufA;  // [M,128]  (region A)
    float* h1  = bufB;  // [M,256]  (region B)
    float* h2  = bufA;  // [M,256]  (region A reused; agg dead after GEMM1)

    // zero flag + agg in one stream-ordered memset
    hipMemsetAsync(ws, 0, 256 + (size_t)M * D_IN * sizeof(float), stream);

    detect_kernel<<<128, 256, 0, stream>>>((const unsigned int*)ei, flag, E);

    int tasks = 2 * E;                       // 1.2M directed edges
    int sblocks = (tasks + 7) / 8;           // 8 edge-tasks per 256-thread block
    scatter_kernel<<<sblocks, 256, 0, stream>>>(x, ei, flag, agg, E);

    dim3 g1((M + 63) / 64, D_HID / 64);
    gemm_kernel<true><<<g1, 256, 0, stream>>>(agg, W1, b1, h1, M, D_HID, D_IN);

    dim3 g2((M + 63) / 64, D_HID / 64);
    gemm_kernel<true><<<g2, 256, 0, stream>>>(h1, W2, b2, h2, M, D_HID, D_HID);

    gemm_ln_kernel<<<(M + 31) / 32, 256, 0, stream>>>(h2, W3, b3, ln_g, ln_b, out, M);
}

// Round 2
// 517.687 us; speedup vs baseline: 4.3849x; 4.3849x over previous
//
#include <hip/hip_runtime.h>
#include <hip/hip_bf16.h>

#define D_IN  128
#define D_HID 256
#define D_OUT 128

__device__ __forceinline__ float gelu_exact(float x) {
    return 0.5f * x * (1.0f + erff(x * 0.70710678118654752f));
}

// Detect edge_index dtype: OR of odd 32-bit words over the first 2E words.
// int64 (values < 50000) -> all high words zero -> flag stays 0. int32 -> nonzero.
__global__ void detect_kernel(const unsigned int* __restrict__ w,
                              unsigned int* __restrict__ flag, int E) {
    unsigned int v = 0;
    for (long long i = (long long)blockIdx.x * blockDim.x + threadIdx.x; i < E;
         i += (long long)gridDim.x * blockDim.x)
        v |= w[2 * i + 1];
    v |= __shfl_xor(v, 32);
    v |= __shfl_xor(v, 16);
    v |= __shfl_xor(v, 8);
    v |= __shfl_xor(v, 4);
    v |= __shfl_xor(v, 2);
    v |= __shfl_xor(v, 1);
    if ((threadIdx.x & 63) == 0 && v) atomicOr(flag, 1u);
}

// Directed-edge decode: task i in [0,2E): e=i>>1, dir=i&1.
// dir=0: s=senders[e], r=receivers[e]; dir=1 swapped. senders=p[0:E], receivers=p[E:2E].
__device__ __forceinline__ void edge_sr(const void* ei, unsigned int flagv, int E,
                                        int e, int dir, int& s, int& r) {
    long long a, b;
    if (flagv == 0u) {  // int64
        const long long* p = (const long long*)ei;
        a = p[e]; b = p[E + e];
    } else {            // int32
        const int* p = (const int*)ei;
        a = p[e]; b = p[E + e];
    }
    if (dir) { s = (int)b; r = (int)a; } else { s = (int)a; r = (int)b; }
}

__global__ void hist_kernel(const void* __restrict__ ei,
                            const unsigned int* __restrict__ flag,
                            int* __restrict__ deg, int E) {
    int i = blockIdx.x * blockDim.x + threadIdx.x;
    if (i >= 2 * E) return;
    int s, r;
    edge_sr(ei, *flag, E, i >> 1, i & 1, s, r);
    atomicAdd(&deg[r], 1);
}

// Single-block exclusive scan: off[i] = sum(deg[0..i-1]); cursor = copy; off[M] = total.
__global__ __launch_bounds__(1024) void scan_kernel(const int* __restrict__ deg,
                                                    int* __restrict__ off,
                                                    int* __restrict__ cursor, int M) {
    __shared__ int wsum[16];
    __shared__ int carry_s;
    int tid = threadIdx.x;
    int wid = tid >> 6;
    if (tid == 0) carry_s = 0;
    __syncthreads();
    for (int base = 0; base < M; base += 1024) {
        int carry = carry_s;
        int i = base + tid;
        int v = (i < M) ? deg[i] : 0;
        int incl = v;
#pragma unroll
        for (int d = 1; d < 64; d <<= 1) {
            int t = __shfl_up(incl, d);
            if ((tid & 63) >= d) incl += t;
        }
        if ((tid & 63) == 63) wsum[wid] = incl;
        __syncthreads();
        if (tid < 16) {
            int wv = wsum[tid];
#pragma unroll
            for (int d = 1; d < 16; d <<= 1) {
                int t = __shfl_up(wv, d);
                if (tid >= d) wv += t;
            }
            wsum[tid] = wv;  // inclusive wave sums
        }
        __syncthreads();
        int waveoff = (wid == 0) ? 0 : wsum[wid - 1];
        int excl = carry + waveoff + incl - v;
        if (i < M) { off[i] = excl; cursor[i] = excl; }
        int total = wsum[15];
        __syncthreads();
        if (tid == 0) carry_s = carry + total;
        __syncthreads();
    }
    if (tid == 0) off[M] = carry_s;
}

__global__ void fill_kernel(const void* __restrict__ ei,
                            const unsigned int* __restrict__ flag,
                            int* __restrict__ cursor, int* __restrict__ csr, int E) {
    int i = blockIdx.x * blockDim.x + threadIdx.x;
    if (i >= 2 * E) return;
    int s, r;
    edge_sr(ei, *flag, E, i >> 1, i & 1, s, r);
    int pos = atomicAdd(&cursor[r], 1);
    csr[pos] = s;
}

// One 32-lane group per node: sum x[src] rows (512B coalesced each), write agg once.
__global__ __launch_bounds__(256) void gather_kernel(
        const float* __restrict__ x, const int* __restrict__ off,
        const int* __restrict__ csr, float* __restrict__ agg, int M) {
    int n = blockIdx.x * 8 + (threadIdx.x >> 5);
    int lane = threadIdx.x & 31;
    if (n >= M) return;
    int beg = off[n], end = off[n + 1];
    float4 a0 = make_float4(0.f, 0.f, 0.f, 0.f);
    float4 a1 = make_float4(0.f, 0.f, 0.f, 0.f);
    int j = beg;
    for (; j + 2 <= end; j += 2) {
        int s0 = csr[j], s1 = csr[j + 1];
        float4 v0 = ((const float4*)(x + (long long)s0 * D_IN))[lane];
        float4 v1 = ((const float4*)(x + (long long)s1 * D_IN))[lane];
        a0.x += v0.x; a0.y += v0.y; a0.z += v0.z; a0.w += v0.w;
        a1.x += v1.x; a1.y += v1.y; a1.z += v1.z; a1.w += v1.w;
    }
    if (j < end) {
        int s0 = csr[j];
        float4 v0 = ((const float4*)(x + (long long)s0 * D_IN))[lane];
        a0.x += v0.x; a0.y += v0.y; a0.z += v0.z; a0.w += v0.w;
    }
    a0.x += a1.x; a0.y += a1.y; a0.z += a1.z; a0.w += a1.w;
    ((float4*)(agg + (long long)n * D_IN))[lane] = a0;
}

// C[M,N] = act(A[M,K] @ B[K,N] + bias). BM=BN=64, BK=16, 256 thr, 4x4/thread.
template<bool GELU>
__global__ __launch_bounds__(256) void gemm_kernel(
        const float* __restrict__ A, const float* __restrict__ B,
        const float* __restrict__ bias, float* __restrict__ C,
        int M, int N, int K) {
    __shared__ float As[16][68];
    __shared__ float Bs[16][68];
    int tid = threadIdx.x;
    int tx = tid & 15, ty = tid >> 4;
    int m0 = blockIdx.x * 64, n0 = blockIdx.y * 64;
    float acc[4][4] = {};
    int arow = tid >> 2, akq = (tid & 3) * 4;   // A: 64 rows x 16 k, float4/thread
    int bkk  = tid >> 4, bn  = (tid & 15) * 4;  // B: 16 k x 64 n, float4/thread

    for (int k0 = 0; k0 < K; k0 += 16) {
        float4 a4 = make_float4(0.f, 0.f, 0.f, 0.f);
        if (m0 + arow < M)
            a4 = *(const float4*)(A + (long long)(m0 + arow) * K + k0 + akq);
        *(float4*)(&Bs[bkk][bn]) = *(const float4*)(B + (long long)(k0 + bkk) * N + n0 + bn);
        As[akq + 0][arow] = a4.x;
        As[akq + 1][arow] = a4.y;
        As[akq + 2][arow] = a4.z;
        As[akq + 3][arow] = a4.w;
        __syncthreads();
#pragma unroll
        for (int kk = 0; kk < 16; ++kk) {
            float4 a = *(const float4*)(&As[kk][ty * 4]);
            float4 b = *(const float4*)(&Bs[kk][tx * 4]);
            float av[4] = {a.x, a.y, a.z, a.w};
            float bv[4] = {b.x, b.y, b.z, b.w};
#pragma unroll
            for (int i = 0; i < 4; ++i)
#pragma unroll
                for (int j = 0; j < 4; ++j)
                    acc[i][j] = fmaf(av[i], bv[j], acc[i][j]);
        }
        __syncthreads();
    }
#pragma unroll
    for (int i = 0; i < 4; ++i) {
        int m = m0 + ty * 4 + i;
        if (m < M) {
            float4 o;
            float* op = (float*)&o;
#pragma unroll
            for (int j = 0; j < 4; ++j) {
                float v = acc[i][j] + bias[n0 + tx * 4 + j];
                op[j] = GELU ? gelu_exact(v) : v;
            }
            *(float4*)(C + (long long)m * N + n0 + tx * 4) = o;
        }
    }
}

// out = LayerNorm(A[M,256] @ W3[256,128] + b3) * g + beta.
// BM=32, BN=128(full), BK=8, 256 thr, 4x4/thread; row in one 32-lane half-wave.
__global__ __launch_bounds__(256) void gemm_ln_kernel(
        const float* __restrict__ A, const float* __restrict__ B,
        const float* __restrict__ bias, const float* __restrict__ g,
        const float* __restrict__ beta, float* __restrict__ out, int M) {
    __shared__ float As[8][36];
    __shared__ float Bs[8][132];
    int tid = threadIdx.x;
    int tx = tid & 31, ty = tid >> 5;
    int m0 = blockIdx.x * 32;
    float acc[4][4] = {};
    int arow = tid >> 3, akq = tid & 7;  // A: 32 rows x 8 k, 1 float/thread

    for (int k0 = 0; k0 < 256; k0 += 8) {
        float av = 0.f;
        if (m0 + arow < M)
            av = A[(long long)(m0 + arow) * 256 + k0 + akq];
        As[akq][arow] = av;
        *(float4*)(&Bs[ty][tx * 4]) = *(const float4*)(B + (long long)(k0 + ty) * 128 + tx * 4);
        __syncthreads();
#pragma unroll
        for (int kk = 0; kk < 8; ++kk) {
            float4 a = *(const float4*)(&As[kk][ty * 4]);
            float4 b = *(const float4*)(&Bs[kk][tx * 4]);
            float av4[4] = {a.x, a.y, a.z, a.w};
            float bv4[4] = {b.x, b.y, b.z, b.w};
#pragma unroll
            for (int i = 0; i < 4; ++i)
#pragma unroll
                for (int j = 0; j < 4; ++j)
                    acc[i][j] = fmaf(av4[i], bv4[j], acc[i][j]);
        }
        __syncthreads();
    }

    float mu[4], rs[4];
#pragma unroll
    for (int i = 0; i < 4; ++i) {
        float s = 0.f, q = 0.f;
#pragma unroll
        for (int j = 0; j < 4; ++j) {
            float v = acc[i][j] + bias[tx * 4 + j];
            acc[i][j] = v;
            s += v;
            q += v * v;
        }
#pragma unroll
        for (int msk = 16; msk >= 1; msk >>= 1) {
            s += __shfl_xor(s, msk);
            q += __shfl_xor(q, msk);
        }
        float m = s * (1.f / 128.f);
        float var = q * (1.f / 128.f) - m * m;
        mu[i] = m;
        rs[i] = rsqrtf(var + 1e-5f);
    }
#pragma unroll
    for (int i = 0; i < 4; ++i) {
        int m = m0 + ty * 4 + i;
        if (m < M) {
            float4 o;
            float* op = (float*)&o;
#pragma unroll
            for (int j = 0; j < 4; ++j)
                op[j] = (acc[i][j] - mu[i]) * rs[i] * g[tx * 4 + j] + beta[tx * 4 + j];
            *(float4*)(out + (long long)m * 128 + tx * 4) = o;
        }
    }
}

extern "C" void kernel_launch(void* const* d_in, const int* in_sizes, int n_in,
                              void* d_out, int out_size, void* d_ws, size_t ws_size,
                              hipStream_t stream) {
    const float* x    = (const float*)d_in[0];
    const void*  ei   = d_in[1];
    const float* W1   = (const float*)d_in[2];
    const float* b1   = (const float*)d_in[3];
    const float* W2   = (const float*)d_in[4];
    const float* b2   = (const float*)d_in[5];
    const float* W3   = (const float*)d_in[6];
    const float* b3   = (const float*)d_in[7];
    const float* ln_g = (const float*)d_in[8];
    const float* ln_b = (const float*)d_in[9];
    float* out = (float*)d_out;

    int M = in_sizes[0] / D_IN;   // 50000 nodes
    int E = in_sizes[1] / 2;      // 600000 edges

    char* ws = (char*)d_ws;
    unsigned int* flag = (unsigned int*)ws;
    size_t regSize = (size_t)M * D_HID * sizeof(float);  // 51.2 MB
    float* bufA = (float*)(ws + 256);
    float* bufB = (float*)(ws + 256 + regSize);
    float* agg = bufA;  // [M,128]  (region A)
    float* h1  = bufB;  // [M,256]  (region B; CSR scratch lives here pre-GEMM1)
    float* h2  = bufA;  // [M,256]  (region A reused; agg dead after GEMM1)

    // CSR scratch inside region B (dead until GEMM1 writes h1)
    int* deg    = (int*)bufB;        // [M]
    int* off    = deg + M;           // [M+1]
    int* cursor = off + M + 1;       // [M]
    int* csr    = cursor + M;        // [2E]

    hipMemsetAsync(ws, 0, 256, stream);                      // flag
    hipMemsetAsync(deg, 0, (size_t)M * sizeof(int), stream); // degree histogram

    detect_kernel<<<128, 256, 0, stream>>>((const unsigned int*)ei, flag, E);

    int tasks = 2 * E;  // 1.2M directed edges
    int tblocks = (tasks + 255) / 256;
    hist_kernel<<<tblocks, 256, 0, stream>>>(ei, flag, deg, E);
    scan_kernel<<<1, 1024, 0, stream>>>(deg, off, cursor, M);
    fill_kernel<<<tblocks, 256, 0, stream>>>(ei, flag, cursor, csr, E);
    gather_kernel<<<(M + 7) / 8, 256, 0, stream>>>(x, off, csr, agg, M);

    dim3 g1((M + 63) / 64, D_HID / 64);
    gemm_kernel<true><<<g1, 256, 0, stream>>>(agg, W1, b1, h1, M, D_HID, D_IN);

    dim3 g2((M + 63) / 64, D_HID / 64);
    gemm_kernel<true><<<g2, 256, 0, stream>>>(h1, W2, b2, h2, M, D_HID, D_HID);

    gemm_ln_kernel<<<(M + 31) / 32, 256, 0, stream>>>(h2, W3, b3, ln_g, ln_b, out, M);
}

// Round 3
// 305.697 us; speedup vs baseline: 7.4256x; 1.6935x over previous
//
#include <hip/hip_runtime.h>
#include <hip/hip_bf16.h>

#define D_IN  128
#define D_HID 256
#define D_OUT 128

typedef __attribute__((ext_vector_type(8))) short short8v;
typedef __attribute__((ext_vector_type(4))) float float4v;

__device__ __forceinline__ float gelu_exact(float x) {
    return 0.5f * x * (1.0f + erff(x * 0.70710678118654752f));
}
__device__ __forceinline__ unsigned short f2bf(float f) {  // RNE
    unsigned int u = __float_as_uint(f);
    return (unsigned short)((u + 0x7FFFu + ((u >> 16) & 1u)) >> 16);
}
__device__ __forceinline__ float bf2f(unsigned short u) {
    return __uint_as_float((unsigned int)u << 16);
}

// ---- edge dtype detect: int64 -> odd words of first E entries all zero ----
__global__ void detect_kernel(const unsigned int* __restrict__ w,
                              unsigned int* __restrict__ flag, int E) {
    unsigned int v = 0;
    for (long long i = (long long)blockIdx.x * blockDim.x + threadIdx.x; i < E;
         i += (long long)gridDim.x * blockDim.x)
        v |= w[2 * i + 1];
    v |= __shfl_xor(v, 32); v |= __shfl_xor(v, 16); v |= __shfl_xor(v, 8);
    v |= __shfl_xor(v, 4);  v |= __shfl_xor(v, 2);  v |= __shfl_xor(v, 1);
    if ((threadIdx.x & 63) == 0 && v) atomicOr(flag, 1u);
}

__device__ __forceinline__ void edge_sr(const void* ei, unsigned int flagv, int E,
                                        int e, int dir, int& s, int& r) {
    long long a, b;
    if (flagv == 0u) { const long long* p = (const long long*)ei; a = p[e]; b = p[E + e]; }
    else             { const int* p = (const int*)ei;            a = p[e]; b = p[E + e]; }
    if (dir) { s = (int)b; r = (int)a; } else { s = (int)a; r = (int)b; }
}

__global__ void hist_kernel(const void* __restrict__ ei,
                            const unsigned int* __restrict__ flag,
                            int* __restrict__ deg, int E) {
    int i = blockIdx.x * blockDim.x + threadIdx.x;
    if (i >= 2 * E) return;
    int s, r;
    edge_sr(ei, *flag, E, i >> 1, i & 1, s, r);
    atomicAdd(&deg[r], 1);
}

// ---- hierarchical scan: A) block sums  B) scan sums  C) per-block rescan ----
__global__ __launch_bounds__(1024) void scanA_kernel(const int* __restrict__ deg,
                                                     int* __restrict__ bsum, int M) {
    __shared__ int wsum[16];
    int tid = threadIdx.x;
    int i = blockIdx.x * 1024 + tid;
    int v = (i < M) ? deg[i] : 0;
#pragma unroll
    for (int m = 32; m >= 1; m >>= 1) v += __shfl_xor(v, m);
    if ((tid & 63) == 0) wsum[tid >> 6] = v;
    __syncthreads();
    if (tid == 0) {
        int s = 0;
#pragma unroll
        for (int k = 0; k < 16; ++k) s += wsum[k];
        bsum[blockIdx.x] = s;
    }
}

__global__ __launch_bounds__(64) void scanB_kernel(int* __restrict__ bsum,
                                                   int* __restrict__ off, int nb, int M) {
    int t = threadIdx.x;
    int v = (t < nb) ? bsum[t] : 0;
    int incl = v;
#pragma unroll
    for (int d = 1; d < 64; d <<= 1) {
        int tv = __shfl_up(incl, d);
        if (t >= d) incl += tv;
    }
    if (t < nb) bsum[t] = incl - v;      // exclusive
    if (t == 63) off[M] = incl;          // grand total
}

__global__ __launch_bounds__(1024) void scanC_kernel(const int* __restrict__ deg,
                                                     const int* __restrict__ bsum,
                                                     int* __restrict__ off,
                                                     int* __restrict__ cursor, int M) {
    __shared__ int wsum[16];
    int tid = threadIdx.x, wid = tid >> 6;
    int i = blockIdx.x * 1024 + tid;
    int v = (i < M) ? deg[i] : 0;
    int incl = v;
#pragma unroll
    for (int d = 1; d < 64; d <<= 1) {
        int t = __shfl_up(incl, d);
        if ((tid & 63) >= d) incl += t;
    }
    if ((tid & 63) == 63) wsum[wid] = incl;
    __syncthreads();
    if (tid < 16) {
        int wv = wsum[tid];
#pragma unroll
        for (int d = 1; d < 16; d <<= 1) {
            int t = __shfl_up(wv, d);
            if (tid >= d) wv += t;
        }
        wsum[tid] = wv;
    }
    __syncthreads();
    int waveoff = (wid == 0) ? 0 : wsum[wid - 1];
    int excl = bsum[blockIdx.x] + waveoff + incl - v;
    if (i < M) { off[i] = excl; cursor[i] = excl; }
}

__global__ void fill_kernel(const void* __restrict__ ei,
                            const unsigned int* __restrict__ flag,
                            int* __restrict__ cursor, int* __restrict__ csr, int E) {
    int i = blockIdx.x * blockDim.x + threadIdx.x;
    if (i >= 2 * E) return;
    int s, r;
    edge_sr(ei, *flag, E, i >> 1, i & 1, s, r);
    int pos = atomicAdd(&cursor[r], 1);
    csr[pos] = s;
}

// ---- convert x to bf16 ----
__global__ __launch_bounds__(256) void xconv_kernel(const float* __restrict__ x,
                                                    unsigned short* __restrict__ xb,
                                                    long long n4) {
    long long i = (long long)blockIdx.x * blockDim.x + threadIdx.x;
    if (i >= n4) return;
    float4 v = ((const float4*)x)[i];
    ushort4 o = { f2bf(v.x), f2bf(v.y), f2bf(v.z), f2bf(v.w) };
    ((ushort4*)xb)[i] = o;
}

// ---- convert + transpose weights: W[K][N] f32 -> Wt[N][K] bf16 ----
__global__ __launch_bounds__(256) void wconv_kernel(
        const float* __restrict__ W1, const float* __restrict__ W2,
        const float* __restrict__ W3, unsigned short* __restrict__ Wt1,
        unsigned short* __restrict__ Wt2, unsigned short* __restrict__ Wt3) {
    int idx = blockIdx.x * blockDim.x + threadIdx.x;
    if (idx < 128 * 256) {
        int k = idx >> 8, n = idx & 255;               // W1 [128][256]
        Wt1[n * 128 + k] = f2bf(W1[idx]);
    } else if (idx < 128 * 256 + 256 * 256) {
        int j = idx - 128 * 256;
        int k = j >> 8, n = j & 255;                   // W2 [256][256]
        Wt2[n * 256 + k] = f2bf(W2[j]);
    } else if (idx < 128 * 256 + 256 * 256 + 256 * 128) {
        int j = idx - (128 * 256 + 256 * 256);
        int k = j >> 7, n = j & 127;                   // W3 [256][128]
        Wt3[n * 256 + k] = f2bf(W3[j]);
    }
}

// ---- gather: one 32-lane group per node, bf16 x, fp32 accumulate, bf16 agg ----
__global__ __launch_bounds__(256) void gather_kernel(
        const unsigned short* __restrict__ xb, const int* __restrict__ off,
        const int* __restrict__ csr, unsigned short* __restrict__ agg, int M) {
    int n = blockIdx.x * 8 + (threadIdx.x >> 5);
    int lane = threadIdx.x & 31;
    if (n >= M) return;
    int beg = off[n], end = off[n + 1];
    float a0 = 0.f, a1 = 0.f, a2 = 0.f, a3 = 0.f;
    float b0 = 0.f, b1 = 0.f, b2 = 0.f, b3 = 0.f;
    int j = beg;
    for (; j + 2 <= end; j += 2) {
        int s0 = csr[j], s1 = csr[j + 1];
        ushort4 u0 = *(const ushort4*)(xb + (long long)s0 * D_IN + lane * 4);
        ushort4 u1 = *(const ushort4*)(xb + (long long)s1 * D_IN + lane * 4);
        a0 += bf2f(u0.x); a1 += bf2f(u0.y); a2 += bf2f(u0.z); a3 += bf2f(u0.w);
        b0 += bf2f(u1.x); b1 += bf2f(u1.y); b2 += bf2f(u1.z); b3 += bf2f(u1.w);
    }
    if (j < end) {
        ushort4 u0 = *(const ushort4*)(xb + (long long)csr[j] * D_IN + lane * 4);
        a0 += bf2f(u0.x); a1 += bf2f(u0.y); a2 += bf2f(u0.z); a3 += bf2f(u0.w);
    }
    ushort4 o = { f2bf(a0 + b0), f2bf(a1 + b1), f2bf(a2 + b2), f2bf(a3 + b3) };
    *(ushort4*)(agg + (long long)n * D_IN + lane * 4) = o;
}

// ---- bf16 MFMA GEMM: C = gelu(A[M,K] @ W + bias), W given as Wt[N][K] bf16.
// BM=BN=64, BK=32, 256 thr = 4 waves (2x2), wave tile 32x32 = 4 MFMAs/K-step.
__global__ __launch_bounds__(256) void gemm_kernel(
        const unsigned short* __restrict__ A, const unsigned short* __restrict__ Wt,
        const float* __restrict__ bias, unsigned short* __restrict__ C,
        int M, int N, int K) {
    __shared__ unsigned short Al[64][40];
    __shared__ unsigned short Bl[64][40];
    int t = threadIdx.x;
    int lane = t & 63, wid = t >> 6;
    int wm = wid >> 1, wn = wid & 1;
    int lr = lane & 15, l4 = (lane >> 4) * 8;
    int m0 = blockIdx.x * 64, n0 = blockIdx.y * 64;

    float4v zero = {0.f, 0.f, 0.f, 0.f};
    float4v acc[2][2];
    acc[0][0] = zero; acc[0][1] = zero; acc[1][0] = zero; acc[1][1] = zero;

    int srow = t >> 2, sc = (t & 3) * 8;
    for (int k0 = 0; k0 < K; k0 += 32) {
        uint4 av = {0u, 0u, 0u, 0u};
        if (m0 + srow < M)
            av = *(const uint4*)(A + (size_t)(m0 + srow) * K + k0 + sc);
        *(uint4*)&Al[srow][sc] = av;
        *(uint4*)&Bl[srow][sc] = *(const uint4*)(Wt + (size_t)(n0 + srow) * K + k0 + sc);
        __syncthreads();
        short8v a0 = *(const short8v*)&Al[wm * 32 + lr][l4];
        short8v a1 = *(const short8v*)&Al[wm * 32 + 16 + lr][l4];
        short8v b0 = *(const short8v*)&Bl[wn * 32 + lr][l4];
        short8v b1 = *(const short8v*)&Bl[wn * 32 + 16 + lr][l4];
        acc[0][0] = __builtin_amdgcn_mfma_f32_16x16x32_bf16(a0, b0, acc[0][0], 0, 0, 0);
        acc[0][1] = __builtin_amdgcn_mfma_f32_16x16x32_bf16(a0, b1, acc[0][1], 0, 0, 0);
        acc[1][0] = __builtin_amdgcn_mfma_f32_16x16x32_bf16(a1, b0, acc[1][0], 0, 0, 0);
        acc[1][1] = __builtin_amdgcn_mfma_f32_16x16x32_bf16(a1, b1, acc[1][1], 0, 0, 0);
        __syncthreads();
    }
#pragma unroll
    for (int fm = 0; fm < 2; ++fm)
#pragma unroll
        for (int fn = 0; fn < 2; ++fn) {
            int col = n0 + wn * 32 + fn * 16 + lr;
            float bv = bias[col];
#pragma unroll
            for (int i = 0; i < 4; ++i) {
                int row = m0 + wm * 32 + fm * 16 + (lane >> 4) * 4 + i;
                if (row < M)
                    C[(size_t)row * N + col] = f2bf(gelu_exact(acc[fm][fn][i] + bv));
            }
        }
}

// ---- GEMM3 + LayerNorm fused: out = LN(A[M,256] @ W3 + b3)*g + beta.
// BM=64, BN=128(full), BK=32; 4 waves, each owns 16 full rows -> shfl LN.
__global__ __launch_bounds__(256) void gemm_ln_kernel(
        const unsigned short* __restrict__ A, const unsigned short* __restrict__ Wt,
        const float* __restrict__ bias, const float* __restrict__ g,
        const float* __restrict__ beta, float* __restrict__ out, int M) {
    __shared__ unsigned short Al[64][40];
    __shared__ unsigned short Bl[128][40];
    int t = threadIdx.x;
    int lane = t & 63, w = t >> 6;
    int lr = lane & 15, l4 = (lane >> 4) * 8;
    int m0 = blockIdx.x * 64;

    float4v zero = {0.f, 0.f, 0.f, 0.f};
    float4v acc[8];
#pragma unroll
    for (int fn = 0; fn < 8; ++fn) acc[fn] = zero;

    int srow = t >> 2, sc = (t & 3) * 8;
    for (int k0 = 0; k0 < 256; k0 += 32) {
        uint4 av = {0u, 0u, 0u, 0u};
        if (m0 + srow < M)
            av = *(const uint4*)(A + (size_t)(m0 + srow) * 256 + k0 + sc);
        *(uint4*)&Al[srow][sc] = av;
        *(uint4*)&Bl[srow][sc]      = *(const uint4*)(Wt + (size_t)srow * 256 + k0 + sc);
        *(uint4*)&Bl[srow + 64][sc] = *(const uint4*)(Wt + (size_t)(srow + 64) * 256 + k0 + sc);
        __syncthreads();
        short8v af = *(const short8v*)&Al[w * 16 + lr][l4];
#pragma unroll
        for (int fn = 0; fn < 8; ++fn) {
            short8v bf = *(const short8v*)&Bl[fn * 16 + lr][l4];
            acc[fn] = __builtin_amdgcn_mfma_f32_16x16x32_bf16(af, bf, acc[fn], 0, 0, 0);
        }
        __syncthreads();
    }

#pragma unroll
    for (int i = 0; i < 4; ++i) {
        float v[8];
        float s = 0.f, q = 0.f;
#pragma unroll
        for (int fn = 0; fn < 8; ++fn) {
            v[fn] = acc[fn][i] + bias[fn * 16 + lr];
            s += v[fn];
            q += v[fn] * v[fn];
        }
#pragma unroll
        for (int msk = 8; msk >= 1; msk >>= 1) {
            s += __shfl_xor(s, msk);
            q += __shfl_xor(q, msk);
        }
        float mu = s * (1.f / 128.f);
        float var = q * (1.f / 128.f) - mu * mu;
        float rs = rsqrtf(var + 1e-5f);
        int row = m0 + w * 16 + (lane >> 4) * 4 + i;
        if (row < M) {
#pragma unroll
            for (int fn = 0; fn < 8; ++fn) {
                int col = fn * 16 + lr;
                out[(size_t)row * 128 + col] = (v[fn] - mu) * rs * g[col] + beta[col];
            }
        }
    }
}

extern "C" void kernel_launch(void* const* d_in, const int* in_sizes, int n_in,
                              void* d_out, int out_size, void* d_ws, size_t ws_size,
                              hipStream_t stream) {
    const float* x    = (const float*)d_in[0];
    const void*  ei   = d_in[1];
    const float* W1   = (const float*)d_in[2];
    const float* b1   = (const float*)d_in[3];
    const float* W2   = (const float*)d_in[4];
    const float* b2   = (const float*)d_in[5];
    const float* W3   = (const float*)d_in[6];
    const float* b3   = (const float*)d_in[7];
    const float* ln_g = (const float*)d_in[8];
    const float* ln_b = (const float*)d_in[9];
    float* out = (float*)d_out;

    int M = in_sizes[0] / D_IN;   // 50000
    int E = in_sizes[1] / 2;      // 600000

    char* ws = (char*)d_ws;
    size_t o = 0;
    unsigned int* flag = (unsigned int*)(ws + o); o += 256;
    unsigned short* Wt1 = (unsigned short*)(ws + o); o += 128 * 256 * 2;
    unsigned short* Wt2 = (unsigned short*)(ws + o); o += 256 * 256 * 2;
    unsigned short* Wt3 = (unsigned short*)(ws + o); o += 128 * 256 * 2;
    unsigned short* xb  = (unsigned short*)(ws + o); o += (size_t)M * D_IN * 2;
    unsigned short* agg = (unsigned short*)(ws + o); o += (size_t)M * D_IN * 2;
    unsigned short* h1  = (unsigned short*)(ws + o); o += (size_t)M * D_HID * 2;
    unsigned short* h2  = (unsigned short*)(ws + o); o += (size_t)M * D_HID * 2;
    int* deg    = (int*)(ws + o); o += (size_t)M * 4;
    int* off    = (int*)(ws + o); o += (size_t)(M + 1) * 4;
    int* cursor = (int*)(ws + o); o += (size_t)M * 4;
    int* csr    = (int*)(ws + o); o += (size_t)2 * E * 4;
    int nb = (M + 1023) / 1024;
    int* bsum   = (int*)(ws + o); o += (size_t)nb * 4;

    hipMemsetAsync(flag, 0, 256, stream);
    hipMemsetAsync(deg, 0, (size_t)M * sizeof(int), stream);

    detect_kernel<<<128, 256, 0, stream>>>((const unsigned int*)ei, flag, E);

    xconv_kernel<<<(int)(((long long)M * D_IN / 4 + 255) / 256), 256, 0, stream>>>(
        x, xb, (long long)M * D_IN / 4);
    wconv_kernel<<<(128 * 256 + 256 * 256 + 256 * 128 + 255) / 256, 256, 0, stream>>>(
        W1, W2, W3, Wt1, Wt2, Wt3);

    int tblocks = (2 * E + 255) / 256;
    hist_kernel<<<tblocks, 256, 0, stream>>>(ei, flag, deg, E);
    scanA_kernel<<<nb, 1024, 0, stream>>>(deg, bsum, M);
    scanB_kernel<<<1, 64, 0, stream>>>(bsum, off, nb, M);
    scanC_kernel<<<nb, 1024, 0, stream>>>(deg, bsum, off, cursor, M);
    fill_kernel<<<tblocks, 256, 0, stream>>>(ei, flag, cursor, csr, E);
    gather_kernel<<<(M + 7) / 8, 256, 0, stream>>>(xb, off, csr, agg, M);

    dim3 g1((M + 63) / 64, D_HID / 64);
    gemm_kernel<<<g1, 256, 0, stream>>>(agg, Wt1, b1, h1, M, D_HID, D_IN);
    gemm_kernel<<<g1, 256, 0, stream>>>(h1, Wt2, b2, h2, M, D_HID, D_HID);
    gemm_ln_kernel<<<(M + 63) / 64, 256, 0, stream>>>(h2, Wt3, b3, ln_g, ln_b, out, M);
}

// Round 4
// 272.986 us; speedup vs baseline: 8.3154x; 1.1198x over previous
//
#include <hip/hip_runtime.h>
#include <hip/hip_bf16.h>

#define D_IN  128
#define D_HID 256
#define D_OUT 128
#define NSHARD 8

typedef __attribute__((ext_vector_type(8))) short short8v;
typedef __attribute__((ext_vector_type(4))) float float4v;

__device__ __forceinline__ float gelu_exact(float x) {
    return 0.5f * x * (1.0f + erff(x * 0.70710678118654752f));
}
__device__ __forceinline__ unsigned short f2bf(float f) {  // RNE
    unsigned int u = __float_as_uint(f);
    return (unsigned short)((u + 0x7FFFu + ((u >> 16) & 1u)) >> 16);
}
__device__ __forceinline__ float bf2f(unsigned short u) {
    return __uint_as_float((unsigned int)u << 16);
}

// ---- edge dtype detect: int64 -> odd words of first E entries all zero ----
__global__ void detect_kernel(const unsigned int* __restrict__ w,
                              unsigned int* __restrict__ flag, int E) {
    unsigned int v = 0;
    for (long long i = (long long)blockIdx.x * blockDim.x + threadIdx.x; i < E;
         i += (long long)gridDim.x * blockDim.x)
        v |= w[2 * i + 1];
    v |= __shfl_xor(v, 32); v |= __shfl_xor(v, 16); v |= __shfl_xor(v, 8);
    v |= __shfl_xor(v, 4);  v |= __shfl_xor(v, 2);  v |= __shfl_xor(v, 1);
    if ((threadIdx.x & 63) == 0 && v) atomicOr(flag, 1u);
}

__device__ __forceinline__ void edge_sr(const void* ei, unsigned int flagv, int E,
                                        int e, int dir, int& s, int& r) {
    long long a, b;
    if (flagv == 0u) { const long long* p = (const long long*)ei; a = p[e]; b = p[E + e]; }
    else             { const int* p = (const int*)ei;            a = p[e]; b = p[E + e]; }
    if (dir) { s = (int)b; r = (int)a; } else { s = (int)a; r = (int)b; }
}

// shard = blockIdx.x & 7 ~ XCD id (round-robin dispatch heuristic); deg is [8][M]
__global__ void hist_kernel(const void* __restrict__ ei,
                            const unsigned int* __restrict__ flag,
                            int* __restrict__ deg, int E, int M) {
    int i = blockIdx.x * blockDim.x + threadIdx.x;
    if (i >= 2 * E) return;
    int shard = blockIdx.x & (NSHARD - 1);
    int s, r;
    edge_sr(ei, *flag, E, i >> 1, i & 1, s, r);
    atomicAdd(&deg[(size_t)shard * M + r], 1);
}

// ---- hierarchical scan over NM = 8*M elements ----
__global__ __launch_bounds__(1024) void scanA_kernel(const int* __restrict__ deg,
                                                     int* __restrict__ bsum, int NM) {
    __shared__ int wsum[16];
    int tid = threadIdx.x;
    int i = blockIdx.x * 1024 + tid;
    int v = (i < NM) ? deg[i] : 0;
#pragma unroll
    for (int m = 32; m >= 1; m >>= 1) v += __shfl_xor(v, m);
    if ((tid & 63) == 0) wsum[tid >> 6] = v;
    __syncthreads();
    if (tid == 0) {
        int s = 0;
#pragma unroll
        for (int k = 0; k < 16; ++k) s += wsum[k];
        bsum[blockIdx.x] = s;
    }
}

// single block, 1024 threads: exclusive-scan bsum[0..nb) (nb <= 1024), total -> off[NM]
__global__ __launch_bounds__(1024) void scanB_kernel(int* __restrict__ bsum,
                                                     int* __restrict__ off,
                                                     int nb, int NM) {
    __shared__ int wsum[16];
    int tid = threadIdx.x, wid = tid >> 6;
    int v = (tid < nb) ? bsum[tid] : 0;
    int incl = v;
#pragma unroll
    for (int d = 1; d < 64; d <<= 1) {
        int t = __shfl_up(incl, d);
        if ((tid & 63) >= d) incl += t;
    }
    if ((tid & 63) == 63) wsum[wid] = incl;
    __syncthreads();
    if (tid < 16) {
        int wv = wsum[tid];
#pragma unroll
        for (int d = 1; d < 16; d <<= 1) {
            int t = __shfl_up(wv, d);
            if (tid >= d) wv += t;
        }
        wsum[tid] = wv;
    }
    __syncthreads();
    int waveoff = (wid == 0) ? 0 : wsum[wid - 1];
    if (tid < nb) bsum[tid] = waveoff + incl - v;   // exclusive
    if (tid == 1023) off[NM] = wsum[15];            // grand total
}

__global__ __launch_bounds__(1024) void scanC_kernel(const int* __restrict__ deg,
                                                     const int* __restrict__ bsum,
                                                     int* __restrict__ off,
                                                     int* __restrict__ cursor, int NM) {
    __shared__ int wsum[16];
    int tid = threadIdx.x, wid = tid >> 6;
    int i = blockIdx.x * 1024 + tid;
    int v = (i < NM) ? deg[i] : 0;
    int incl = v;
#pragma unroll
    for (int d = 1; d < 64; d <<= 1) {
        int t = __shfl_up(incl, d);
        if ((tid & 63) >= d) incl += t;
    }
    if ((tid & 63) == 63) wsum[wid] = incl;
    __syncthreads();
    if (tid < 16) {
        int wv = wsum[tid];
#pragma unroll
        for (int d = 1; d < 16; d <<= 1) {
            int t = __shfl_up(wv, d);
            if (tid >= d) wv += t;
        }
        wsum[tid] = wv;
    }
    __syncthreads();
    int waveoff = (wid == 0) ? 0 : wsum[wid - 1];
    int excl = bsum[blockIdx.x] + waveoff + incl - v;
    if (i < NM) { off[i] = excl; cursor[i] = excl; }
}

__global__ void fill_kernel(const void* __restrict__ ei,
                            const unsigned int* __restrict__ flag,
                            int* __restrict__ cursor, int* __restrict__ csr,
                            int E, int M) {
    int i = blockIdx.x * blockDim.x + threadIdx.x;
    if (i >= 2 * E) return;
    int shard = blockIdx.x & (NSHARD - 1);
    int s, r;
    edge_sr(ei, *flag, E, i >> 1, i & 1, s, r);
    int pos = atomicAdd(&cursor[(size_t)shard * M + r], 1);
    csr[pos] = s;
}

// ---- convert x to bf16 ----
__global__ __launch_bounds__(256) void xconv_kernel(const float* __restrict__ x,
                                                    unsigned short* __restrict__ xb,
                                                    long long n4) {
    long long i = (long long)blockIdx.x * blockDim.x + threadIdx.x;
    if (i >= n4) return;
    float4 v = ((const float4*)x)[i];
    ushort4 o = { f2bf(v.x), f2bf(v.y), f2bf(v.z), f2bf(v.w) };
    ((ushort4*)xb)[i] = o;
}

// ---- convert + transpose weights: W[K][N] f32 -> Wt[N][K] bf16 ----
__global__ __launch_bounds__(256) void wconv_kernel(
        const float* __restrict__ W1, const float* __restrict__ W2,
        const float* __restrict__ W3, unsigned short* __restrict__ Wt1,
        unsigned short* __restrict__ Wt2, unsigned short* __restrict__ Wt3) {
    int idx = blockIdx.x * blockDim.x + threadIdx.x;
    if (idx < 128 * 256) {
        int k = idx >> 8, n = idx & 255;               // W1 [128][256]
        Wt1[n * 128 + k] = f2bf(W1[idx]);
    } else if (idx < 128 * 256 + 256 * 256) {
        int j = idx - 128 * 256;
        int k = j >> 8, n = j & 255;                   // W2 [256][256]
        Wt2[n * 256 + k] = f2bf(W2[j]);
    } else if (idx < 128 * 256 + 256 * 256 + 256 * 128) {
        int j = idx - (128 * 256 + 256 * 256);
        int k = j >> 7, n = j & 127;                   // W3 [256][128]
        Wt3[n * 256 + k] = f2bf(W3[j]);
    }
}

// ---- gather: one 32-lane group per node; 8 shard segments; fp32 acc; bf16 out ----
__global__ __launch_bounds__(256) void gather_kernel(
        const unsigned short* __restrict__ xb, const int* __restrict__ off,
        const int* __restrict__ csr, unsigned short* __restrict__ agg, int M) {
    int n = blockIdx.x * 8 + (threadIdx.x >> 5);
    int lane = threadIdx.x & 31;
    if (n >= M) return;
    float a0 = 0.f, a1 = 0.f, a2 = 0.f, a3 = 0.f;
    float b0 = 0.f, b1 = 0.f, b2 = 0.f, b3 = 0.f;
#pragma unroll
    for (int s = 0; s < NSHARD; ++s) {
        int j = off[(size_t)s * M + n];
        int end = off[(size_t)s * M + n + 1];
        for (; j + 2 <= end; j += 2) {
            int s0 = csr[j], s1 = csr[j + 1];
            ushort4 u0 = *(const ushort4*)(xb + (long long)s0 * D_IN + lane * 4);
            ushort4 u1 = *(const ushort4*)(xb + (long long)s1 * D_IN + lane * 4);
            a0 += bf2f(u0.x); a1 += bf2f(u0.y); a2 += bf2f(u0.z); a3 += bf2f(u0.w);
            b0 += bf2f(u1.x); b1 += bf2f(u1.y); b2 += bf2f(u1.z); b3 += bf2f(u1.w);
        }
        if (j < end) {
            ushort4 u0 = *(const ushort4*)(xb + (long long)csr[j] * D_IN + lane * 4);
            a0 += bf2f(u0.x); a1 += bf2f(u0.y); a2 += bf2f(u0.z); a3 += bf2f(u0.w);
        }
    }
    ushort4 o = { f2bf(a0 + b0), f2bf(a1 + b1), f2bf(a2 + b2), f2bf(a3 + b3) };
    *(ushort4*)(agg + (long long)n * D_IN + lane * 4) = o;
}

// ---- bf16 MFMA GEMM: C = gelu(A[M,K] @ W + bias), W given as Wt[N][K] bf16.
// BM=BN=64, BK=32, 256 thr = 4 waves (2x2), wave tile 32x32 = 4 MFMAs/K-step.
__global__ __launch_bounds__(256) void gemm_kernel(
        const unsigned short* __restrict__ A, const unsigned short* __restrict__ Wt,
        const float* __restrict__ bias, unsigned short* __restrict__ C,
        int M, int N, int K) {
    __shared__ unsigned short Al[64][40];
    __shared__ unsigned short Bl[64][40];
    int t = threadIdx.x;
    int lane = t & 63, wid = t >> 6;
    int wm = wid >> 1, wn = wid & 1;
    int lr = lane & 15, l4 = (lane >> 4) * 8;
    int m0 = blockIdx.x * 64, n0 = blockIdx.y * 64;

    float4v zero = {0.f, 0.f, 0.f, 0.f};
    float4v acc[2][2];
    acc[0][0] = zero; acc[0][1] = zero; acc[1][0] = zero; acc[1][1] = zero;

    int srow = t >> 2, sc = (t & 3) * 8;
    for (int k0 = 0; k0 < K; k0 += 32) {
        uint4 av = {0u, 0u, 0u, 0u};
        if (m0 + srow < M)
            av = *(const uint4*)(A + (size_t)(m0 + srow) * K + k0 + sc);
        *(uint4*)&Al[srow][sc] = av;
        *(uint4*)&Bl[srow][sc] = *(const uint4*)(Wt + (size_t)(n0 + srow) * K + k0 + sc);
        __syncthreads();
        short8v a0 = *(const short8v*)&Al[wm * 32 + lr][l4];
        short8v a1 = *(const short8v*)&Al[wm * 32 + 16 + lr][l4];
        short8v b0 = *(const short8v*)&Bl[wn * 32 + lr][l4];
        short8v b1 = *(const short8v*)&Bl[wn * 32 + 16 + lr][l4];
        acc[0][0] = __builtin_amdgcn_mfma_f32_16x16x32_bf16(a0, b0, acc[0][0], 0, 0, 0);
        acc[0][1] = __builtin_amdgcn_mfma_f32_16x16x32_bf16(a0, b1, acc[0][1], 0, 0, 0);
        acc[1][0] = __builtin_amdgcn_mfma_f32_16x16x32_bf16(a1, b0, acc[1][0], 0, 0, 0);
        acc[1][1] = __builtin_amdgcn_mfma_f32_16x16x32_bf16(a1, b1, acc[1][1], 0, 0, 0);
        __syncthreads();
    }
#pragma unroll
    for (int fm = 0; fm < 2; ++fm)
#pragma unroll
        for (int fn = 0; fn < 2; ++fn) {
            int col = n0 + wn * 32 + fn * 16 + lr;
            float bv = bias[col];
#pragma unroll
            for (int i = 0; i < 4; ++i) {
                int row = m0 + wm * 32 + fm * 16 + (lane >> 4) * 4 + i;
                if (row < M)
                    C[(size_t)row * N + col] = f2bf(gelu_exact(acc[fm][fn][i] + bv));
            }
        }
}

// ---- GEMM3 + LayerNorm fused: out = LN(A[M,256] @ W3 + b3)*g + beta.
// BM=64, BN=128(full), BK=32; 4 waves, each owns 16 full rows -> shfl LN.
__global__ __launch_bounds__(256) void gemm_ln_kernel(
        const unsigned short* __restrict__ A, const unsigned short* __restrict__ Wt,
        const float* __restrict__ bias, const float* __restrict__ g,
        const float* __restrict__ beta, float* __restrict__ out, int M) {
    __shared__ unsigned short Al[64][40];
    __shared__ unsigned short Bl[128][40];
    int t = threadIdx.x;
    int lane = t & 63, w = t >> 6;
    int lr = lane & 15, l4 = (lane >> 4) * 8;
    int m0 = blockIdx.x * 64;

    float4v zero = {0.f, 0.f, 0.f, 0.f};
    float4v acc[8];
#pragma unroll
    for (int fn = 0; fn < 8; ++fn) acc[fn] = zero;

    int srow = t >> 2, sc = (t & 3) * 8;
    for (int k0 = 0; k0 < 256; k0 += 32) {
        uint4 av = {0u, 0u, 0u, 0u};
        if (m0 + srow < M)
            av = *(const uint4*)(A + (size_t)(m0 + srow) * 256 + k0 + sc);
        *(uint4*)&Al[srow][sc] = av;
        *(uint4*)&Bl[srow][sc]      = *(const uint4*)(Wt + (size_t)srow * 256 + k0 + sc);
        *(uint4*)&Bl[srow + 64][sc] = *(const uint4*)(Wt + (size_t)(srow + 64) * 256 + k0 + sc);
        __syncthreads();
        short8v af = *(const short8v*)&Al[w * 16 + lr][l4];
#pragma unroll
        for (int fn = 0; fn < 8; ++fn) {
            short8v bf = *(const short8v*)&Bl[fn * 16 + lr][l4];
            acc[fn] = __builtin_amdgcn_mfma_f32_16x16x32_bf16(af, bf, acc[fn], 0, 0, 0);
        }
        __syncthreads();
    }

#pragma unroll
    for (int i = 0; i < 4; ++i) {
        float v[8];
        float s = 0.f, q = 0.f;
#pragma unroll
        for (int fn = 0; fn < 8; ++fn) {
            v[fn] = acc[fn][i] + bias[fn * 16 + lr];
            s += v[fn];
            q += v[fn] * v[fn];
        }
#pragma unroll
        for (int msk = 8; msk >= 1; msk >>= 1) {
            s += __shfl_xor(s, msk);
            q += __shfl_xor(q, msk);
        }
        float mu = s * (1.f / 128.f);
        float var = q * (1.f / 128.f) - mu * mu;
        float rs = rsqrtf(var + 1e-5f);
        int row = m0 + w * 16 + (lane >> 4) * 4 + i;
        if (row < M) {
#pragma unroll
            for (int fn = 0; fn < 8; ++fn) {
                int col = fn * 16 + lr;
                out[(size_t)row * 128 + col] = (v[fn] - mu) * rs * g[col] + beta[col];
            }
        }
    }
}

extern "C" void kernel_launch(void* const* d_in, const int* in_sizes, int n_in,
                              void* d_out, int out_size, void* d_ws, size_t ws_size,
                              hipStream_t stream) {
    const float* x    = (const float*)d_in[0];
    const void*  ei   = d_in[1];
    const float* W1   = (const float*)d_in[2];
    const float* b1   = (const float*)d_in[3];
    const float* W2   = (const float*)d_in[4];
    const float* b2   = (const float*)d_in[5];
    const float* W3   = (const float*)d_in[6];
    const float* b3   = (const float*)d_in[7];
    const float* ln_g = (const float*)d_in[8];
    const float* ln_b = (const float*)d_in[9];
    float* out = (float*)d_out;

    int M = in_sizes[0] / D_IN;   // 50000
    int E = in_sizes[1] / 2;      // 600000
    int NM = NSHARD * M;          // 400000

    char* ws = (char*)d_ws;
    size_t o = 0;
    unsigned int* flag = (unsigned int*)(ws + o); o += 256;
    unsigned short* Wt1 = (unsigned short*)(ws + o); o += 128 * 256 * 2;
    unsigned short* Wt2 = (unsigned short*)(ws + o); o += 256 * 256 * 2;
    unsigned short* Wt3 = (unsigned short*)(ws + o); o += 128 * 256 * 2;
    unsigned short* xb  = (unsigned short*)(ws + o); o += (size_t)M * D_IN * 2;
    unsigned short* agg = (unsigned short*)(ws + o); o += (size_t)M * D_IN * 2;
    unsigned short* h1  = (unsigned short*)(ws + o); o += (size_t)M * D_HID * 2;
    unsigned short* h2  = (unsigned short*)(ws + o); o += (size_t)M * D_HID * 2;
    int* deg    = (int*)(ws + o); o += (size_t)NM * 4;
    int* off    = (int*)(ws + o); o += (size_t)(NM + 1) * 4;
    int* cursor = (int*)(ws + o); o += (size_t)NM * 4;
    int* csr    = (int*)(ws + o); o += (size_t)2 * E * 4;
    int nb = (NM + 1023) / 1024;  // 391
    int* bsum   = (int*)(ws + o); o += (size_t)nb * 4;

    hipMemsetAsync(flag, 0, 256, stream);
    hipMemsetAsync(deg, 0, (size_t)NM * sizeof(int), stream);

    detect_kernel<<<128, 256, 0, stream>>>((const unsigned int*)ei, flag, E);

    xconv_kernel<<<(int)(((long long)M * D_IN / 4 + 255) / 256), 256, 0, stream>>>(
        x, xb, (long long)M * D_IN / 4);
    wconv_kernel<<<(128 * 256 + 256 * 256 + 256 * 128 + 255) / 256, 256, 0, stream>>>(
        W1, W2, W3, Wt1, Wt2, Wt3);

    int tblocks = (2 * E + 255) / 256;
    hist_kernel<<<tblocks, 256, 0, stream>>>(ei, flag, deg, E, M);
    scanA_kernel<<<nb, 1024, 0, stream>>>(deg, bsum, NM);
    scanB_kernel<<<1, 1024, 0, stream>>>(bsum, off, nb, NM);
    scanC_kernel<<<nb, 1024, 0, stream>>>(deg, bsum, off, cursor, NM);
    fill_kernel<<<tblocks, 256, 0, stream>>>(ei, flag, cursor, csr, E, M);
    gather_kernel<<<(M + 7) / 8, 256, 0, stream>>>(xb, off, csr, agg, M);

    dim3 g1((M + 63) / 64, D_HID / 64);
    gemm_kernel<<<g1, 256, 0, stream>>>(agg, Wt1, b1, h1, M, D_HID, D_IN);
    gemm_kernel<<<g1, 256, 0, stream>>>(h1, Wt2, b2, h2, M, D_HID, D_HID);
    gemm_ln_kernel<<<(M + 63) / 64, 256, 0, stream>>>(h2, Wt3, b3, ln_g, ln_b, out, M);
}

// Round 5
// 266.430 us; speedup vs baseline: 8.5200x; 1.0246x over previous
//
#include <hip/hip_runtime.h>
#include <hip/hip_bf16.h>

#define D_IN  128
#define D_HID 256
#define D_OUT 128
#define NSHARD 8

typedef __attribute__((ext_vector_type(8))) short short8v;
typedef __attribute__((ext_vector_type(4))) float float4v;

__device__ __forceinline__ float gelu_exact(float x) {
    return 0.5f * x * (1.0f + erff(x * 0.70710678118654752f));
}
__device__ __forceinline__ unsigned short f2bf(float f) {  // RNE
    unsigned int u = __float_as_uint(f);
    return (unsigned short)((u + 0x7FFFu + ((u >> 16) & 1u)) >> 16);
}
__device__ __forceinline__ float bf2f(unsigned short u) {
    return __uint_as_float((unsigned int)u << 16);
}
__device__ __forceinline__ float bflo(unsigned int w) {
    return __uint_as_float(w << 16);
}
__device__ __forceinline__ float bfhi(unsigned int w) {
    return __uint_as_float(w & 0xFFFF0000u);
}
__device__ __forceinline__ unsigned int pack2(float lo, float hi) {
    return (unsigned int)f2bf(lo) | ((unsigned int)f2bf(hi) << 16);
}

// ---- edge dtype detect: int64 -> odd words of first E entries all zero ----
__global__ void detect_kernel(const unsigned int* __restrict__ w,
                              unsigned int* __restrict__ flag, int E) {
    unsigned int v = 0;
    for (long long i = (long long)blockIdx.x * blockDim.x + threadIdx.x; i < E;
         i += (long long)gridDim.x * blockDim.x)
        v |= w[2 * i + 1];
    v |= __shfl_xor(v, 32); v |= __shfl_xor(v, 16); v |= __shfl_xor(v, 8);
    v |= __shfl_xor(v, 4);  v |= __shfl_xor(v, 2);  v |= __shfl_xor(v, 1);
    if ((threadIdx.x & 63) == 0 && v) atomicOr(flag, 1u);
}

__device__ __forceinline__ void edge_pair(const void* ei, unsigned int flagv, int E,
                                          int e, int& s, int& r) {
    if (flagv == 0u) { const long long* p = (const long long*)ei; s = (int)p[e]; r = (int)p[E + e]; }
    else             { const int* p = (const int*)ei;            s = p[e];      r = p[E + e]; }
}

// One thread per UNDIRECTED edge: both directions. shard = blockIdx.x & 7 ~ XCD.
__global__ void hist_kernel(const void* __restrict__ ei,
                            const unsigned int* __restrict__ flag,
                            int* __restrict__ deg, int E, int M) {
    int e = blockIdx.x * blockDim.x + threadIdx.x;
    if (e >= E) return;
    int shard = blockIdx.x & (NSHARD - 1);
    int s, r;
    edge_pair(ei, *flag, E, e, s, r);
    atomicAdd(&deg[(size_t)shard * M + r], 1);
    atomicAdd(&deg[(size_t)shard * M + s], 1);
}

// ---- hierarchical scan (works for any N; bsum length <= 1024) ----
__global__ __launch_bounds__(1024) void scanA_kernel(const int* __restrict__ deg,
                                                     int* __restrict__ bsum, int NM) {
    __shared__ int wsum[16];
    int tid = threadIdx.x;
    int i = blockIdx.x * 1024 + tid;
    int v = (i < NM) ? deg[i] : 0;
#pragma unroll
    for (int m = 32; m >= 1; m >>= 1) v += __shfl_xor(v, m);
    if ((tid & 63) == 0) wsum[tid >> 6] = v;
    __syncthreads();
    if (tid == 0) {
        int s = 0;
#pragma unroll
        for (int k = 0; k < 16; ++k) s += wsum[k];
        bsum[blockIdx.x] = s;
    }
}

__global__ __launch_bounds__(1024) void scanB_kernel(int* __restrict__ bsum,
                                                     int* __restrict__ off,
                                                     int nb, int NM) {
    __shared__ int wsum[16];
    int tid = threadIdx.x, wid = tid >> 6;
    int v = (tid < nb) ? bsum[tid] : 0;
    int incl = v;
#pragma unroll
    for (int d = 1; d < 64; d <<= 1) {
        int t = __shfl_up(incl, d);
        if ((tid & 63) >= d) incl += t;
    }
    if ((tid & 63) == 63) wsum[wid] = incl;
    __syncthreads();
    if (tid < 16) {
        int wv = wsum[tid];
#pragma unroll
        for (int d = 1; d < 16; d <<= 1) {
            int t = __shfl_up(wv, d);
            if (tid >= d) wv += t;
        }
        wsum[tid] = wv;
    }
    __syncthreads();
    int waveoff = (wid == 0) ? 0 : wsum[wid - 1];
    if (tid < nb) bsum[tid] = waveoff + incl - v;   // exclusive
    if (tid == 1023) off[NM] = wsum[15];            // grand total
}

__global__ __launch_bounds__(1024) void scanC_kernel(const int* __restrict__ deg,
                                                     const int* __restrict__ bsum,
                                                     int* __restrict__ off,
                                                     int* __restrict__ cursor, int NM) {
    __shared__ int wsum[16];
    int tid = threadIdx.x, wid = tid >> 6;
    int i = blockIdx.x * 1024 + tid;
    int v = (i < NM) ? deg[i] : 0;
    int incl = v;
#pragma unroll
    for (int d = 1; d < 64; d <<= 1) {
        int t = __shfl_up(incl, d);
        if ((tid & 63) >= d) incl += t;
    }
    if ((tid & 63) == 63) wsum[wid] = incl;
    __syncthreads();
    if (tid < 16) {
        int wv = wsum[tid];
#pragma unroll
        for (int d = 1; d < 16; d <<= 1) {
            int t = __shfl_up(wv, d);
            if (tid >= d) wv += t;
        }
        wsum[tid] = wv;
    }
    __syncthreads();
    int waveoff = (wid == 0) ? 0 : wsum[wid - 1];
    int excl = bsum[blockIdx.x] + waveoff + incl - v;
    if (i < NM) { off[i] = excl; cursor[i] = excl; }
}

// One thread per UNDIRECTED edge: append s to r's list and r to s's list.
__global__ void fill_kernel(const void* __restrict__ ei,
                            const unsigned int* __restrict__ flag,
                            int* __restrict__ cursor, int* __restrict__ csr,
                            int E, int M) {
    int e = blockIdx.x * blockDim.x + threadIdx.x;
    if (e >= E) return;
    int shard = blockIdx.x & (NSHARD - 1);
    int s, r;
    edge_pair(ei, *flag, E, e, s, r);
    int pr = atomicAdd(&cursor[(size_t)shard * M + r], 1);
    csr[pr] = s;
    int ps = atomicAdd(&cursor[(size_t)shard * M + s], 1);
    csr[ps] = r;
}

// deg2[n] = sum over shards of deg[s][n]
__global__ __launch_bounds__(256) void degsum_kernel(const int* __restrict__ deg,
                                                     int* __restrict__ deg2, int M) {
    int n = blockIdx.x * blockDim.x + threadIdx.x;
    if (n >= M) return;
    int t = 0;
#pragma unroll
    for (int k = 0; k < NSHARD; ++k) t += deg[(size_t)k * M + n];
    deg2[n] = t;
}

// csr (shard-major) -> csr2 (node-major); 1 thread per node.
__global__ __launch_bounds__(256) void repack_kernel(const int* __restrict__ off,
                                                     const int* __restrict__ off2,
                                                     const int* __restrict__ csr,
                                                     int* __restrict__ csr2, int M) {
    int n = blockIdx.x * blockDim.x + threadIdx.x;
    if (n >= M) return;
    int w = off2[n];
#pragma unroll
    for (int s = 0; s < NSHARD; ++s) {
        int j = off[(size_t)s * M + n];
        int e = off[(size_t)s * M + n + 1];
        for (; j < e; ++j) csr2[w++] = csr[j];
    }
}

// ---- convert x to bf16 ----
__global__ __launch_bounds__(256) void xconv_kernel(const float* __restrict__ x,
                                                    unsigned short* __restrict__ xb,
                                                    long long n4) {
    long long i = (long long)blockIdx.x * blockDim.x + threadIdx.x;
    if (i >= n4) return;
    float4 v = ((const float4*)x)[i];
    ushort4 o = { f2bf(v.x), f2bf(v.y), f2bf(v.z), f2bf(v.w) };
    ((ushort4*)xb)[i] = o;
}

// ---- convert + transpose weights: W[K][N] f32 -> Wt[N][K] bf16 ----
__global__ __launch_bounds__(256) void wconv_kernel(
        const float* __restrict__ W1, const float* __restrict__ W2,
        const float* __restrict__ W3, unsigned short* __restrict__ Wt1,
        unsigned short* __restrict__ Wt2, unsigned short* __restrict__ Wt3) {
    int idx = blockIdx.x * blockDim.x + threadIdx.x;
    if (idx < 128 * 256) {
        int k = idx >> 8, n = idx & 255;               // W1 [128][256]
        Wt1[n * 128 + k] = f2bf(W1[idx]);
    } else if (idx < 128 * 256 + 256 * 256) {
        int j = idx - 128 * 256;
        int k = j >> 8, n = j & 255;                   // W2 [256][256]
        Wt2[n * 256 + k] = f2bf(W2[j]);
    } else if (idx < 128 * 256 + 256 * 256 + 256 * 128) {
        int j = idx - (128 * 256 + 256 * 256);
        int k = j >> 7, n = j & 127;                   // W3 [256][128]
        Wt3[n * 256 + k] = f2bf(W3[j]);
    }
}

// ---- gather v2: 16-lane group per node (lane = 16B of row), unroll-4,
//      dual accumulator banks, node-major csr2 ----
__global__ __launch_bounds__(256) void gather_kernel(
        const unsigned short* __restrict__ xb, const int* __restrict__ off2,
        const int* __restrict__ csr2, unsigned short* __restrict__ agg, int M) {
    int n = blockIdx.x * 16 + (threadIdx.x >> 4);
    int l = threadIdx.x & 15;
    if (n >= M) return;
    int j = off2[n], end = off2[n + 1];
    float a[8] = {0.f, 0.f, 0.f, 0.f, 0.f, 0.f, 0.f, 0.f};
    float b[8] = {0.f, 0.f, 0.f, 0.f, 0.f, 0.f, 0.f, 0.f};
    const size_t lo = (size_t)l * 8;
    for (; j + 4 <= end; j += 4) {
        int s0 = csr2[j], s1 = csr2[j + 1], s2 = csr2[j + 2], s3 = csr2[j + 3];
        uint4 u0 = *(const uint4*)(xb + (size_t)s0 * D_IN + lo);
        uint4 u1 = *(const uint4*)(xb + (size_t)s1 * D_IN + lo);
        uint4 u2 = *(const uint4*)(xb + (size_t)s2 * D_IN + lo);
        uint4 u3 = *(const uint4*)(xb + (size_t)s3 * D_IN + lo);
        a[0] += bflo(u0.x); a[1] += bfhi(u0.x); a[2] += bflo(u0.y); a[3] += bfhi(u0.y);
        a[4] += bflo(u0.z); a[5] += bfhi(u0.z); a[6] += bflo(u0.w); a[7] += bfhi(u0.w);
        b[0] += bflo(u1.x); b[1] += bfhi(u1.x); b[2] += bflo(u1.y); b[3] += bfhi(u1.y);
        b[4] += bflo(u1.z); b[5] += bfhi(u1.z); b[6] += bflo(u1.w); b[7] += bfhi(u1.w);
        a[0] += bflo(u2.x); a[1] += bfhi(u2.x); a[2] += bflo(u2.y); a[3] += bfhi(u2.y);
        a[4] += bflo(u2.z); a[5] += bfhi(u2.z); a[6] += bflo(u2.w); a[7] += bfhi(u2.w);
        b[0] += bflo(u3.x); b[1] += bfhi(u3.x); b[2] += bflo(u3.y); b[3] += bfhi(u3.y);
        b[4] += bflo(u3.z); b[5] += bfhi(u3.z); b[6] += bflo(u3.w); b[7] += bfhi(u3.w);
    }
    for (; j < end; ++j) {
        uint4 u0 = *(const uint4*)(xb + (size_t)csr2[j] * D_IN + lo);
        a[0] += bflo(u0.x); a[1] += bfhi(u0.x); a[2] += bflo(u0.y); a[3] += bfhi(u0.y);
        a[4] += bflo(u0.z); a[5] += bfhi(u0.z); a[6] += bflo(u0.w); a[7] += bfhi(u0.w);
    }
    uint4 o;
    o.x = pack2(a[0] + b[0], a[1] + b[1]);
    o.y = pack2(a[2] + b[2], a[3] + b[3]);
    o.z = pack2(a[4] + b[4], a[5] + b[5]);
    o.w = pack2(a[6] + b[6], a[7] + b[7]);
    *(uint4*)(agg + (size_t)n * D_IN + lo) = o;
}

// ---- bf16 MFMA GEMM: C = gelu(A[M,K] @ W + bias), W given as Wt[N][K] bf16.
__global__ __launch_bounds__(256) void gemm_kernel(
        const unsigned short* __restrict__ A, const unsigned short* __restrict__ Wt,
        const float* __restrict__ bias, unsigned short* __restrict__ C,
        int M, int N, int K) {
    __shared__ unsigned short Al[64][40];
    __shared__ unsigned short Bl[64][40];
    int t = threadIdx.x;
    int lane = t & 63, wid = t >> 6;
    int wm = wid >> 1, wn = wid & 1;
    int lr = lane & 15, l4 = (lane >> 4) * 8;
    int m0 = blockIdx.x * 64, n0 = blockIdx.y * 64;

    float4v zero = {0.f, 0.f, 0.f, 0.f};
    float4v acc[2][2];
    acc[0][0] = zero; acc[0][1] = zero; acc[1][0] = zero; acc[1][1] = zero;

    int srow = t >> 2, sc = (t & 3) * 8;
    for (int k0 = 0; k0 < K; k0 += 32) {
        uint4 av = {0u, 0u, 0u, 0u};
        if (m0 + srow < M)
            av = *(const uint4*)(A + (size_t)(m0 + srow) * K + k0 + sc);
        *(uint4*)&Al[srow][sc] = av;
        *(uint4*)&Bl[srow][sc] = *(const uint4*)(Wt + (size_t)(n0 + srow) * K + k0 + sc);
        __syncthreads();
        short8v a0 = *(const short8v*)&Al[wm * 32 + lr][l4];
        short8v a1 = *(const short8v*)&Al[wm * 32 + 16 + lr][l4];
        short8v b0 = *(const short8v*)&Bl[wn * 32 + lr][l4];
        short8v b1 = *(const short8v*)&Bl[wn * 32 + 16 + lr][l4];
        acc[0][0] = __builtin_amdgcn_mfma_f32_16x16x32_bf16(a0, b0, acc[0][0], 0, 0, 0);
        acc[0][1] = __builtin_amdgcn_mfma_f32_16x16x32_bf16(a0, b1, acc[0][1], 0, 0, 0);
        acc[1][0] = __builtin_amdgcn_mfma_f32_16x16x32_bf16(a1, b0, acc[1][0], 0, 0, 0);
        acc[1][1] = __builtin_amdgcn_mfma_f32_16x16x32_bf16(a1, b1, acc[1][1], 0, 0, 0);
        __syncthreads();
    }
#pragma unroll
    for (int fm = 0; fm < 2; ++fm)
#pragma unroll
        for (int fn = 0; fn < 2; ++fn) {
            int col = n0 + wn * 32 + fn * 16 + lr;
            float bv = bias[col];
#pragma unroll
            for (int i = 0; i < 4; ++i) {
                int row = m0 + wm * 32 + fm * 16 + (lane >> 4) * 4 + i;
                if (row < M)
                    C[(size_t)row * N + col] = f2bf(gelu_exact(acc[fm][fn][i] + bv));
            }
        }
}

// ---- GEMM3 + LayerNorm fused ----
__global__ __launch_bounds__(256) void gemm_ln_kernel(
        const unsigned short* __restrict__ A, const unsigned short* __restrict__ Wt,
        const float* __restrict__ bias, const float* __restrict__ g,
        const float* __restrict__ beta, float* __restrict__ out, int M) {
    __shared__ unsigned short Al[64][40];
    __shared__ unsigned short Bl[128][40];
    int t = threadIdx.x;
    int lane = t & 63, w = t >> 6;
    int lr = lane & 15, l4 = (lane >> 4) * 8;
    int m0 = blockIdx.x * 64;

    float4v zero = {0.f, 0.f, 0.f, 0.f};
    float4v acc[8];
#pragma unroll
    for (int fn = 0; fn < 8; ++fn) acc[fn] = zero;

    int srow = t >> 2, sc = (t & 3) * 8;
    for (int k0 = 0; k0 < 256; k0 += 32) {
        uint4 av = {0u, 0u, 0u, 0u};
        if (m0 + srow < M)
            av = *(const uint4*)(A + (size_t)(m0 + srow) * 256 + k0 + sc);
        *(uint4*)&Al[srow][sc] = av;
        *(uint4*)&Bl[srow][sc]      = *(const uint4*)(Wt + (size_t)srow * 256 + k0 + sc);
        *(uint4*)&Bl[srow + 64][sc] = *(const uint4*)(Wt + (size_t)(srow + 64) * 256 + k0 + sc);
        __syncthreads();
        short8v af = *(const short8v*)&Al[w * 16 + lr][l4];
#pragma unroll
        for (int fn = 0; fn < 8; ++fn) {
            short8v bf = *(const short8v*)&Bl[fn * 16 + lr][l4];
            acc[fn] = __builtin_amdgcn_mfma_f32_16x16x32_bf16(af, bf, acc[fn], 0, 0, 0);
        }
        __syncthreads();
    }

#pragma unroll
    for (int i = 0; i < 4; ++i) {
        float v[8];
        float s = 0.f, q = 0.f;
#pragma unroll
        for (int fn = 0; fn < 8; ++fn) {
            v[fn] = acc[fn][i] + bias[fn * 16 + lr];
            s += v[fn];
            q += v[fn] * v[fn];
        }
#pragma unroll
        for (int msk = 8; msk >= 1; msk >>= 1) {
            s += __shfl_xor(s, msk);
            q += __shfl_xor(q, msk);
        }
        float mu = s * (1.f / 128.f);
        float var = q * (1.f / 128.f) - mu * mu;
        float rs = rsqrtf(var + 1e-5f);
        int row = m0 + w * 16 + (lane >> 4) * 4 + i;
        if (row < M) {
#pragma unroll
            for (int fn = 0; fn < 8; ++fn) {
                int col = fn * 16 + lr;
                out[(size_t)row * 128 + col] = (v[fn] - mu) * rs * g[col] + beta[col];
            }
        }
    }
}

extern "C" void kernel_launch(void* const* d_in, const int* in_sizes, int n_in,
                              void* d_out, int out_size, void* d_ws, size_t ws_size,
                              hipStream_t stream) {
    const float* x    = (const float*)d_in[0];
    const void*  ei   = d_in[1];
    const float* W1   = (const float*)d_in[2];
    const float* b1   = (const float*)d_in[3];
    const float* W2   = (const float*)d_in[4];
    const float* b2   = (const float*)d_in[5];
    const float* W3   = (const float*)d_in[6];
    const float* b3   = (const float*)d_in[7];
    const float* ln_g = (const float*)d_in[8];
    const float* ln_b = (const float*)d_in[9];
    float* out = (float*)d_out;

    int M = in_sizes[0] / D_IN;   // 50000
    int E = in_sizes[1] / 2;      // 600000
    int NM = NSHARD * M;          // 400000

    char* ws = (char*)d_ws;
    size_t o = 0;
    unsigned int* flag = (unsigned int*)(ws + o); o += 256;
    unsigned short* Wt1 = (unsigned short*)(ws + o); o += 128 * 256 * 2;
    unsigned short* Wt2 = (unsigned short*)(ws + o); o += 256 * 256 * 2;
    unsigned short* Wt3 = (unsigned short*)(ws + o); o += 128 * 256 * 2;
    unsigned short* xb  = (unsigned short*)(ws + o); o += (size_t)M * D_IN * 2;
    unsigned short* agg = (unsigned short*)(ws + o); o += (size_t)M * D_IN * 2;
    unsigned short* h1  = (unsigned short*)(ws + o); o += (size_t)M * D_HID * 2;
    unsigned short* h2  = (unsigned short*)(ws + o); o += (size_t)M * D_HID * 2;
    int* deg    = (int*)(ws + o); o += (size_t)NM * 4;
    int* off    = (int*)(ws + o); o += (size_t)(NM + 1) * 4;
    int* cursor = (int*)(ws + o); o += (size_t)NM * 4;
    int* csr    = (int*)(ws + o); o += (size_t)2 * E * 4;
    int* csr2   = (int*)(ws + o); o += (size_t)2 * E * 4;
    int* deg2   = (int*)(ws + o); o += (size_t)M * 4;
    int* off2   = (int*)(ws + o); o += (size_t)(M + 1) * 4;
    int nb  = (NM + 1023) / 1024;  // 391
    int nbM = (M + 1023) / 1024;   // 49
    int* bsum   = (int*)(ws + o); o += (size_t)nb * 4;
    int* bsum2  = (int*)(ws + o); o += (size_t)nbM * 4;

    hipMemsetAsync(flag, 0, 256, stream);
    hipMemsetAsync(deg, 0, (size_t)NM * sizeof(int), stream);

    detect_kernel<<<128, 256, 0, stream>>>((const unsigned int*)ei, flag, E);

    xconv_kernel<<<(int)(((long long)M * D_IN / 4 + 255) / 256), 256, 0, stream>>>(
        x, xb, (long long)M * D_IN / 4);
    wconv_kernel<<<(128 * 256 + 256 * 256 + 256 * 128 + 255) / 256, 256, 0, stream>>>(
        W1, W2, W3, Wt1, Wt2, Wt3);

    int eblocks = (E + 255) / 256;
    hist_kernel<<<eblocks, 256, 0, stream>>>(ei, flag, deg, E, M);

    // shard-major scan -> off, cursor
    scanA_kernel<<<nb, 1024, 0, stream>>>(deg, bsum, NM);
    scanB_kernel<<<1, 1024, 0, stream>>>(bsum, off, nb, NM);
    scanC_kernel<<<nb, 1024, 0, stream>>>(deg, bsum, off, cursor, NM);

    // node-major scan -> off2 (deg2 doubles as scanC's cursor output; dead after)
    degsum_kernel<<<(M + 255) / 256, 256, 0, stream>>>(deg, deg2, M);
    scanA_kernel<<<nbM, 1024, 0, stream>>>(deg2, bsum2, M);
    scanB_kernel<<<1, 1024, 0, stream>>>(bsum2, off2, nbM, M);
    scanC_kernel<<<nbM, 1024, 0, stream>>>(deg2, bsum2, off2, deg2, M);

    fill_kernel<<<eblocks, 256, 0, stream>>>(ei, flag, cursor, csr, E, M);
    repack_kernel<<<(M + 255) / 256, 256, 0, stream>>>(off, off2, csr, csr2, M);
    gather_kernel<<<(M + 15) / 16, 256, 0, stream>>>(xb, off2, csr2, agg, M);

    dim3 g1((M + 63) / 64, D_HID / 64);
    gemm_kernel<<<g1, 256, 0, stream>>>(agg, Wt1, b1, h1, M, D_HID, D_IN);
    gemm_kernel<<<g1, 256, 0, stream>>>(h1, Wt2, b2, h2, M, D_HID, D_HID);
    gemm_ln_kernel<<<(M + 63) / 64, 256, 0, stream>>>(h2, Wt3, b3, ln_g, ln_b, out, M);
}